// Round 9
// baseline (206.525 us; speedup 1.0000x reference)
//
#include <hip/hip_runtime.h>
#include <math.h>

namespace {

typedef __attribute__((ext_vector_type(8))) short s16x8;
typedef __attribute__((ext_vector_type(4))) float f32x4;
typedef unsigned int u32;
typedef unsigned short u16;

constexpr int B_ = 2;
constexpr int T_ = 2048;
constexpr int C_ = 1024;
constexpr int H_ = 16;
constexpr float L2E = 1.44269504088896340736f;

__device__ inline u16 f2bf(float x) {
    __bf16 h = (__bf16)x;
    return __builtin_bit_cast(u16, h);
}
__device__ inline u32 packbf2(float a, float b) {
    return (u32)f2bf(a) | ((u32)f2bf(b) << 16);
}
__device__ inline void gload_lds16(const void* g, void* lds) {
    __builtin_amdgcn_global_load_lds(
        (const __attribute__((address_space(1))) unsigned int*)g,
        (__attribute__((address_space(3))) unsigned int*)lds, 16, 0, 0);
}

#define VMW(n) asm volatile("s_waitcnt vmcnt(" #n ")" ::: "memory")
#define LGW0() asm volatile("s_waitcnt lgkmcnt(0)" ::: "memory")
#define BARRIER() do { __builtin_amdgcn_s_barrier(); asm volatile("" ::: "memory"); } while (0)
#define SB0() __builtin_amdgcn_sched_barrier(0)
#define PRIO1() __builtin_amdgcn_s_setprio(1)
#define PRIO0() __builtin_amdgcn_s_setprio(0)

// ---------------------------------------------------------------- RoPE table
__global__ __launch_bounds__(256) void tab_k(float2* __restrict__ cs) {
    int idx = blockIdx.x * 256 + threadIdx.x;   // 65536
    int t = idx >> 5, i = idx & 31;
    float inv = 1.0f / powf(10000.0f, (float)i / 32.0f);
    float ang = (float)t * inv;
    cs[idx] = make_float2(cosf(ang), sinf(ang));
}

// ---------------------------------------------------------------- f32 -> bf16 convert
__global__ __launch_bounds__(256)
void cvt_k(const float4* __restrict__ x, const float4* __restrict__ wq,
           const float4* __restrict__ wo, uint2* __restrict__ xb,
           uint2* __restrict__ wqb, uint2* __restrict__ wob) {
    int i = blockIdx.x * 256 + threadIdx.x;   // 2097152 total
    const float4* s;
    uint2* d;
    int j;
    if (i < 1048576) { s = x; d = xb; j = i; }
    else if (i < 1048576 + 786432) { s = wq; d = wqb; j = i - 1048576; }
    else { s = wo; d = wob; j = i - (1048576 + 786432); }
    float4 v = s[j];
    d[j] = make_uint2(packbf2(v.x, v.y), packbf2(v.z, v.w));
}

// ---------------------------------------------------------------- QKV: 256^2 8-phase MFMA GEMM + RoPE
// BM=BN=256, BK=64, 8 waves (2M x 4N), per-wave C = 128x64 (Mrep 8, Nrep 4).
// LDS 128KB: A = 2 tiles x 2 halves x (128 rows x 64 k x 2B = 16KB); B same at +64KB.
// 8 phases / 2 K-tiles; one half-tile staged per phase into a buffer that is
// DEAD since a prior barrier; counted vmcnt(4) at phases 4 & 8 only.
// Swizzle: lds[row][slot^(row&7)] both sides (pre-swizzled global src + swz read).
__global__ __launch_bounds__(512, 2)
void qkv_mfma_k(const u16* __restrict__ xb, const u16* __restrict__ wqb,
                const float2* __restrict__ cs, u16* __restrict__ qb,
                u16* __restrict__ kb, u16* __restrict__ vt) {
    extern __shared__ char lds[];
    const int tid = threadIdx.x;
    const int w = tid >> 6, lane = tid & 63;
    const int c = lane & 15, g = lane >> 4;
    const int n0 = blockIdx.x * 256, m0 = blockIdx.y * 256;
    const int wr = w >> 2, wc = w & 3;

    f32x4 acc[8][4];
#pragma unroll
    for (int i = 0; i < 8; ++i)
#pragma unroll
        for (int j = 0; j < 4; ++j) acc[i][j] = (f32x4){0.f, 0.f, 0.f, 0.f};

    const u16* Ab = xb + (size_t)m0 * C_;
    const u16* Bb = wqb + (size_t)n0 * C_;
    const int srow = tid >> 3, sslot = tid & 7;   // srow 0..63, sslot 0..7

    // stage one 16KB half-tile (128 rows x 64 k): 2 gload_lds16 per thread.
    auto stA = [&](int t, int hf) {
        char* base = lds + (((t & 1) * 2 + hf) << 14);
        const u16* src = Ab + (size_t)(hf * 128) * C_ + t * 64;
#pragma unroll
        for (int call = 0; call < 2; ++call) {
            int row = call * 64 + srow;
            int s = sslot ^ (row & 7);
            gload_lds16(src + (size_t)row * C_ + s * 8, base + call * 8192 + w * 1024);
        }
    };
    auto stB = [&](int t, int hf) {
        char* base = lds + 65536 + (((t & 1) * 2 + hf) << 14);
        const u16* src = Bb + (size_t)(hf * 128) * C_ + t * 64;
#pragma unroll
        for (int call = 0; call < 2; ++call) {
            int row = call * 64 + srow;
            int s = sslot ^ (row & 7);
            gload_lds16(src + (size_t)row * C_ + s * 8, base + call * 8192 + w * 1024);
        }
    };
    auto ldA = [&](int P, int mrep, int kh) -> s16x8 {
        const char* base = lds + ((P * 2 + wr) << 14);
        int row = mrep * 16 + c;
        return *(const s16x8*)(base + row * 128 + (((kh * 4 + g) ^ (row & 7)) * 16));
    };
    auto ldB = [&](int P, int nrep, int kh) -> s16x8 {
        int rowg = wc * 64 + nrep * 16 + c;
        int hf = rowg >> 7, row = rowg & 127;
        const char* base = lds + 65536 + ((P * 2 + hf) << 14);
        return *(const s16x8*)(base + row * 128 + (((kh * 4 + g) ^ (row & 7)) * 16));
    };

    s16x8 aA[4][2], bB0[2][2], bB1[2][2];

    // prologue: t0 fully + t1's B halves; vmcnt(4) leaves t1-B in flight.
    stA(0, 0); stA(0, 1); stB(0, 0); stB(0, 1); stB(1, 0); stB(1, 1);
    VMW(4); BARRIER();

#pragma unroll 1
    for (int i = 0; i < 8; ++i) {
        const int tb_ = 2 * i + 1;
        const bool nl = (i < 7);
        // ================= K-tile 2i (parity 0) =================
        // -- phase 1: A m0-3 + B n0-1 (12 ds_reads); stage (t+1)A h0
#pragma unroll
        for (int mm = 0; mm < 4; ++mm)
#pragma unroll
            for (int kh = 0; kh < 2; ++kh) aA[mm][kh] = ldA(0, mm, kh);
#pragma unroll
        for (int nn = 0; nn < 2; ++nn)
#pragma unroll
            for (int kh = 0; kh < 2; ++kh) bB0[nn][kh] = ldB(0, nn, kh);
        stA(tb_, 0);
        BARRIER(); LGW0(); SB0();
        PRIO1();
#pragma unroll
        for (int kh = 0; kh < 2; ++kh)
#pragma unroll
            for (int mm = 0; mm < 4; ++mm)
#pragma unroll
                for (int nn = 0; nn < 2; ++nn)
                    acc[mm][nn] = __builtin_amdgcn_mfma_f32_16x16x32_bf16(aA[mm][kh], bB0[nn][kh], acc[mm][nn], 0, 0, 0);
        PRIO0();
        BARRIER();
        // -- phase 2: B n2-3 (4 ds_reads); stage (t+1)A h1
#pragma unroll
        for (int nn = 0; nn < 2; ++nn)
#pragma unroll
            for (int kh = 0; kh < 2; ++kh) bB1[nn][kh] = ldB(0, 2 + nn, kh);
        stA(tb_, 1);
        BARRIER(); LGW0(); SB0();
        PRIO1();
#pragma unroll
        for (int kh = 0; kh < 2; ++kh)
#pragma unroll
            for (int mm = 0; mm < 4; ++mm)
#pragma unroll
                for (int nn = 0; nn < 2; ++nn)
                    acc[mm][2 + nn] = __builtin_amdgcn_mfma_f32_16x16x32_bf16(aA[mm][kh], bB1[nn][kh], acc[mm][2 + nn], 0, 0, 0);
        PRIO0();
        BARRIER();
        // -- phase 3: A m4-7 (8 ds_reads); stage (t+2)B h0
#pragma unroll
        for (int mm = 0; mm < 4; ++mm)
#pragma unroll
            for (int kh = 0; kh < 2; ++kh) aA[mm][kh] = ldA(0, 4 + mm, kh);
        if (nl) stB(2 * i + 2, 0);
        BARRIER(); LGW0(); SB0();
        PRIO1();
#pragma unroll
        for (int kh = 0; kh < 2; ++kh)
#pragma unroll
            for (int mm = 0; mm < 4; ++mm)
#pragma unroll
                for (int nn = 0; nn < 2; ++nn)
                    acc[4 + mm][nn] = __builtin_amdgcn_mfma_f32_16x16x32_bf16(aA[mm][kh], bB0[nn][kh], acc[4 + mm][nn], 0, 0, 0);
        PRIO0();
        BARRIER();
        // -- phase 4: no ds_reads; stage (t+2)B h1; counted vmcnt
        if (nl) { stB(2 * i + 2, 1); VMW(4); } else { VMW(0); }
        BARRIER(); SB0();
        PRIO1();
#pragma unroll
        for (int kh = 0; kh < 2; ++kh)
#pragma unroll
            for (int mm = 0; mm < 4; ++mm)
#pragma unroll
                for (int nn = 0; nn < 2; ++nn)
                    acc[4 + mm][2 + nn] = __builtin_amdgcn_mfma_f32_16x16x32_bf16(aA[mm][kh], bB1[nn][kh], acc[4 + mm][2 + nn], 0, 0, 0);
        PRIO0();
        BARRIER();
        // ================= K-tile 2i+1 (parity 1) =================
        // -- phase 5: A m0-3 + B n0-1; stage (t+2)A h0
#pragma unroll
        for (int mm = 0; mm < 4; ++mm)
#pragma unroll
            for (int kh = 0; kh < 2; ++kh) aA[mm][kh] = ldA(1, mm, kh);
#pragma unroll
        for (int nn = 0; nn < 2; ++nn)
#pragma unroll
            for (int kh = 0; kh < 2; ++kh) bB0[nn][kh] = ldB(1, nn, kh);
        if (nl) stA(2 * i + 2, 0);
        BARRIER(); LGW0(); SB0();
        PRIO1();
#pragma unroll
        for (int kh = 0; kh < 2; ++kh)
#pragma unroll
            for (int mm = 0; mm < 4; ++mm)
#pragma unroll
                for (int nn = 0; nn < 2; ++nn)
                    acc[mm][nn] = __builtin_amdgcn_mfma_f32_16x16x32_bf16(aA[mm][kh], bB0[nn][kh], acc[mm][nn], 0, 0, 0);
        PRIO0();
        BARRIER();
        // -- phase 6: B n2-3; stage (t+2)A h1
#pragma unroll
        for (int nn = 0; nn < 2; ++nn)
#pragma unroll
            for (int kh = 0; kh < 2; ++kh) bB1[nn][kh] = ldB(1, 2 + nn, kh);
        if (nl) stA(2 * i + 2, 1);
        BARRIER(); LGW0(); SB0();
        PRIO1();
#pragma unroll
        for (int kh = 0; kh < 2; ++kh)
#pragma unroll
            for (int mm = 0; mm < 4; ++mm)
#pragma unroll
                for (int nn = 0; nn < 2; ++nn)
                    acc[mm][2 + nn] = __builtin_amdgcn_mfma_f32_16x16x32_bf16(aA[mm][kh], bB1[nn][kh], acc[mm][2 + nn], 0, 0, 0);
        PRIO0();
        BARRIER();
        // -- phase 7: A m4-7; stage (t+3)B h0
#pragma unroll
        for (int mm = 0; mm < 4; ++mm)
#pragma unroll
            for (int kh = 0; kh < 2; ++kh) aA[mm][kh] = ldA(1, 4 + mm, kh);
        if (nl) stB(2 * i + 3, 0);
        BARRIER(); LGW0(); SB0();
        PRIO1();
#pragma unroll
        for (int kh = 0; kh < 2; ++kh)
#pragma unroll
            for (int mm = 0; mm < 4; ++mm)
#pragma unroll
                for (int nn = 0; nn < 2; ++nn)
                    acc[4 + mm][nn] = __builtin_amdgcn_mfma_f32_16x16x32_bf16(aA[mm][kh], bB0[nn][kh], acc[4 + mm][nn], 0, 0, 0);
        PRIO0();
        BARRIER();
        // -- phase 8: no ds_reads; stage (t+3)B h1; counted vmcnt
        if (nl) { stB(2 * i + 3, 1); VMW(4); }
        BARRIER(); SB0();
        PRIO1();
#pragma unroll
        for (int kh = 0; kh < 2; ++kh)
#pragma unroll
            for (int mm = 0; mm < 4; ++mm)
#pragma unroll
                for (int nn = 0; nn < 2; ++nn)
                    acc[4 + mm][2 + nn] = __builtin_amdgcn_mfma_f32_16x16x32_bf16(aA[mm][kh], bB1[nn][kh], acc[4 + mm][2 + nn], 0, 0, 0);
        PRIO0();
        BARRIER();
    }

    // epilogue
    const int sec = n0 >> 10;
    const int hD = ((n0 & 1023) >> 6) + wc;
    const int b = m0 >> 11;
    const int t0w = (m0 & 2047) + wr * 128;
    const int bh = b * H_ + hD;
    if (sec < 2) {
        u16* dst = (sec == 0) ? qb : kb;
        const float qs = (sec == 0) ? 0.125f : 1.0f;
#pragma unroll
        for (int nf = 0; nf < 4; ++nf) {
            int d = nf * 16 + c;
            int ibase = nf * 8 + (c >> 1);
#pragma unroll
            for (int mf = 0; mf < 8; ++mf) {
#pragma unroll
                for (int r = 0; r < 4; ++r) {
                    int t = t0w + mf * 16 + g * 4 + r;
                    float own = acc[mf][nf][r];
                    float partner = __shfl_xor(own, 1);
                    float2 csv = cs[t * 32 + ibase];
                    float rot = (d & 1) ? (own * csv.x + partner * csv.y)
                                        : (own * csv.x - partner * csv.y);
                    rot *= qs;
                    float rothi = __shfl_xor(rot, 1);
                    if (!(d & 1))
                        *(u32*)(dst + ((size_t)bh * T_ + t) * 64 + d) = packbf2(rot, rothi);
                }
            }
        }
    } else {
#pragma unroll
        for (int nf = 0; nf < 4; ++nf) {
            int d = nf * 16 + c;
#pragma unroll
            for (int mf = 0; mf < 8; ++mf) {
                int tb2 = t0w + mf * 16 + g * 4;
                u32 lo = packbf2(acc[mf][nf][0], acc[mf][nf][1]);
                u32 hi = packbf2(acc[mf][nf][2], acc[mf][nf][3]);
                *(uint2*)(vt + ((size_t)bh * 64 + d) * T_ + tb2) = make_uint2(lo, hi);
            }
        }
    }
}

// ---------------------------------------------------------------- flash attention (bf16 MFMA)
__global__ __launch_bounds__(256)
void flash_mfma_k(const u16* __restrict__ qb, const u16* __restrict__ kb,
                  const u16* __restrict__ vt, u16* __restrict__ attb) {
    __shared__ char lds[32768];
    char* Qs = lds;                // 8KB: 64 rows x 128B, swz ^((row&7)<<4)
    char* Ks = lds + 8192;         // 8KB
    char* Vs = lds + 16384;        // 8KB: V^T tile (rows = d)
    char* Ps = lds + 24576;        // 8KB: per-wave 2KB, 16 rows x 128B
    const int tid = threadIdx.x, w = tid >> 6, lane = tid & 63;
    const int c = lane & 15, g = lane >> 4;
    const int bh = blockIdx.x;
    const int qi = 31 - blockIdx.y;          // heavy tiles dispatch first
    const int q0 = qi * 64, q0w = q0 + w * 16;
    const u16* Qg = qb + ((size_t)bh * T_ + q0) * 64;
    const u16* Kg = kb + (size_t)bh * T_ * 64;
    const u16* Vg = vt + (size_t)bh * 64 * T_;

#pragma unroll
    for (int call = 0; call < 2; ++call) {
        int row = call * 32 + (tid >> 3);
        int ds = (tid & 7) ^ (row & 7);
        gload_lds16(Qg + (size_t)row * 64 + ds * 8, Qs + call * 4096 + w * 1024);
    }
    __syncthreads();

    s16x8 bQ[2];
#pragma unroll
    for (int kc = 0; kc < 2; ++kc) {
        int row = w * 16 + c;
        bQ[kc] = *(const s16x8*)(Qs + row * 128 + (((kc * 4 + g) ^ (row & 7)) * 16));
    }

    float m_ = -INFINITY, l_ = 0.f;
    f32x4 accO[4];
#pragma unroll
    for (int j = 0; j < 4; ++j) accO[j] = (f32x4){0.f, 0.f, 0.f, 0.f};

    const int nt = qi + 1;
    for (int kt = 0; kt < nt; ++kt) {
        __syncthreads();
        {
            int row = tid >> 3, slot = tid & 7;
#pragma unroll
            for (int call = 0; call < 2; ++call) {
                int r = call * 32 + row;
                int ds = slot ^ (r & 7);
                gload_lds16(Kg + (size_t)(kt * 64 + r) * 64 + ds * 8, Ks + call * 4096 + w * 1024);
                gload_lds16(Vg + (size_t)r * T_ + kt * 64 + ds * 8, Vs + call * 4096 + w * 1024);
            }
        }
        __syncthreads();

        f32x4 S[4];
#pragma unroll
        for (int mf = 0; mf < 4; ++mf) S[mf] = (f32x4){0.f, 0.f, 0.f, 0.f};
        s16x8 aK[4][2];
#pragma unroll
        for (int mf = 0; mf < 4; ++mf)
#pragma unroll
            for (int kc = 0; kc < 2; ++kc) {
                int row = mf * 16 + c;
                aK[mf][kc] = *(const s16x8*)(Ks + row * 128 + (((kc * 4 + g) ^ (row & 7)) * 16));
            }
#pragma unroll
        for (int kc = 0; kc < 2; ++kc)
#pragma unroll
            for (int mf = 0; mf < 4; ++mf)
                S[mf] = __builtin_amdgcn_mfma_f32_16x16x32_bf16(aK[mf][kc], bQ[kc], S[mf], 0, 0, 0);

        if (kt == qi) {
#pragma unroll
            for (int mf = 0; mf < 4; ++mf)
#pragma unroll
                for (int r = 0; r < 4; ++r) {
                    int kvg = kt * 64 + mf * 16 + g * 4 + r;
                    if (kvg > q0w + c) S[mf][r] = -INFINITY;
                }
        }

        float mx = -INFINITY;
#pragma unroll
        for (int mf = 0; mf < 4; ++mf)
#pragma unroll
            for (int r = 0; r < 4; ++r) mx = fmaxf(mx, S[mf][r]);
        mx = fmaxf(mx, __shfl_xor(mx, 16));
        mx = fmaxf(mx, __shfl_xor(mx, 32));
        float alpha = 1.0f;
        if (!__all(mx - m_ <= 8.0f)) {
            float mnew = fmaxf(m_, mx);
            alpha = exp2f((m_ - mnew) * L2E);
            m_ = mnew;
#pragma unroll
            for (int r = 0; r < 4; ++r) {
                float ar = __shfl(alpha, g * 4 + r);
#pragma unroll
                for (int nd = 0; nd < 4; ++nd) accO[nd][r] *= ar;
            }
        }
        float sum = 0.f;
#pragma unroll
        for (int mf = 0; mf < 4; ++mf)
#pragma unroll
            for (int r = 0; r < 4; ++r) {
                float p = exp2f((S[mf][r] - m_) * L2E);
                S[mf][r] = p;
                sum += p;
            }
        sum += __shfl_xor(sum, 16);
        sum += __shfl_xor(sum, 32);
        l_ = l_ * alpha + sum;

#pragma unroll
        for (int mf = 0; mf < 4; ++mf)
#pragma unroll
            for (int p2 = 0; p2 < 2; ++p2) {
                u32 v = packbf2(S[mf][2 * p2], S[mf][2 * p2 + 1]);
                int off = (mf * 16 + g * 4 + p2 * 2) * 2;
                *(u32*)(Ps + w * 2048 + c * 128 + (off ^ ((c & 7) << 4))) = v;
            }
        __threadfence_block();

        s16x8 aP[2], bV[4][2];
#pragma unroll
        for (int kc = 0; kc < 2; ++kc)
            aP[kc] = *(const s16x8*)(Ps + w * 2048 + c * 128 + (((kc * 4 + g) ^ (c & 7)) * 16));
#pragma unroll
        for (int nd = 0; nd < 4; ++nd)
#pragma unroll
            for (int kc = 0; kc < 2; ++kc) {
                int row = nd * 16 + c;
                bV[nd][kc] = *(const s16x8*)(Vs + row * 128 + (((kc * 4 + g) ^ (row & 7)) * 16));
            }
#pragma unroll
        for (int kc = 0; kc < 2; ++kc)
#pragma unroll
            for (int nd = 0; nd < 4; ++nd)
                accO[nd] = __builtin_amdgcn_mfma_f32_16x16x32_bf16(aP[kc], bV[nd][kc], accO[nd], 0, 0, 0);
    }

    const int hh = bh & 15;
    const int bb = bh >> 4;
#pragma unroll
    for (int r = 0; r < 4; ++r) {
        float linv = 1.0f / __shfl(l_, g * 4 + r);
        int t = q0w + g * 4 + r;
        size_t rowb = ((size_t)bb * T_ + t) * C_ + hh * 64;
#pragma unroll
        for (int nd = 0; nd < 4; ++nd)
            attb[rowb + nd * 16 + c] = f2bf(accO[nd][r] * linv);
    }
}

// ---------------------------------------------------------------- out-proj MFMA GEMM + bias
// 3-buffer counted-vmcnt 128^2 structure (round-7, proven)
__global__ __launch_bounds__(256)
void proj_mfma_k(const u16* __restrict__ attb, const u16* __restrict__ wob,
                 const float* __restrict__ bias, float* __restrict__ out) {
    __shared__ char lds[49152];
    char* const b0 = lds;
    char* const b1 = lds + 16384;
    char* const b2 = lds + 32768;
    const int tid = threadIdx.x;
    const int w = tid >> 6, lane = tid & 63;
    const int c = lane & 15, g = lane >> 4;
    const int n0 = blockIdx.x * 128, m0 = blockIdx.y * 128;
    const int wr = w >> 1, wc = w & 1;

    f32x4 acc[4][4];
#pragma unroll
    for (int i = 0; i < 4; ++i)
#pragma unroll
        for (int j = 0; j < 4; ++j) acc[i][j] = (f32x4){0.f, 0.f, 0.f, 0.f};

    const u16* Ab = attb + (size_t)m0 * C_;
    const u16* Bb = wob + (size_t)n0 * C_;
    const int srow = tid >> 2, sslot = tid & 3;

    auto stage = [&](int t, char* base) {
        int k0 = t * 32;
#pragma unroll
        for (int call = 0; call < 2; ++call) {
            int r = call * 64 + srow;
            int ds = sslot ^ ((r >> 1) & 3);
            gload_lds16(Ab + (size_t)r * C_ + k0 + ds * 8, base + call * 4096 + w * 1024);
            gload_lds16(Bb + (size_t)r * C_ + k0 + ds * 8, base + 8192 + call * 4096 + w * 1024);
        }
    };
    auto compute = [&](const char* base) {
        s16x8 aF[4], bF[4];
#pragma unroll
        for (int mf = 0; mf < 4; ++mf) {
            int row = wr * 64 + mf * 16 + c;
            aF[mf] = *(const s16x8*)(base + row * 64 + ((g ^ ((row >> 1) & 3)) * 16));
        }
#pragma unroll
        for (int nf = 0; nf < 4; ++nf) {
            int row = wc * 64 + nf * 16 + c;
            bF[nf] = *(const s16x8*)(base + 8192 + row * 64 + ((g ^ ((row >> 1) & 3)) * 16));
        }
#pragma unroll
        for (int mf = 0; mf < 4; ++mf)
#pragma unroll
            for (int nf = 0; nf < 4; ++nf)
                acc[mf][nf] = __builtin_amdgcn_mfma_f32_16x16x32_bf16(aF[mf], bF[nf], acc[mf][nf], 0, 0, 0);
    };

    stage(0, b0);
    stage(1, b1);
#pragma unroll 1
    for (int t = 0; t < 30; t += 3) {
        VMW(4); BARRIER(); stage(t + 2, b2); compute(b0); LGW0();
        VMW(4); BARRIER(); stage(t + 3, b0); compute(b1); LGW0();
        VMW(4); BARRIER(); stage(t + 4, b1); compute(b2); LGW0();
    }
    VMW(4); BARRIER(); compute(b0); LGW0();   // t = 30
    VMW(0); BARRIER(); compute(b1);           // t = 31

#pragma unroll
    for (int nf = 0; nf < 4; ++nf) {
        int n = n0 + wc * 64 + nf * 16 + c;
        float bv = bias[n];
#pragma unroll
        for (int mf = 0; mf < 4; ++mf)
#pragma unroll
            for (int r = 0; r < 4; ++r) {
                int mrow = m0 + wr * 64 + mf * 16 + g * 4 + r;
                out[(size_t)mrow * C_ + n] = acc[mf][nf][r] + bv;
            }
    }
}

} // namespace

extern "C" void kernel_launch(void* const* d_in, const int* in_sizes, int n_in,
                              void* d_out, int out_size, void* d_ws, size_t ws_size,
                              hipStream_t stream) {
    const float* x     = (const float*)d_in[0];
    const float* w_qkv = (const float*)d_in[1];
    const float* w_out = (const float*)d_in[2];
    const float* b_out = (const float*)d_in[3];
    float* out = (float*)d_out;

    char* ws = (char*)d_ws;
    float2* cs = (float2*)ws;                               // 512KB
    u16* xb   = (u16*)(ws + 524288);                        // 8MB
    u16* wqb  = (u16*)(ws + 524288 + 8388608);              // 6MB
    u16* wob  = (u16*)(ws + 524288 + 8388608 + 6291456);    // 2MB
    u16* qb   = (u16*)(ws + 17301504);                      // 8MB
    u16* kb   = (u16*)(ws + 25690112);                      // 8MB
    u16* vt   = (u16*)(ws + 34078720);                      // 8MB
    u16* attb = (u16*)(ws + 42467328);                      // 8MB

    // allow 128KB dynamic LDS for the 256^2 kernel (no-op if already set)
    (void)hipFuncSetAttribute((const void*)qkv_mfma_k,
                              hipFuncAttributeMaxDynamicSharedMemorySize, 131072);

    tab_k<<<256, 256, 0, stream>>>(cs);
    cvt_k<<<8192, 256, 0, stream>>>((const float4*)x, (const float4*)w_qkv,
                                    (const float4*)w_out, (uint2*)xb, (uint2*)wqb, (uint2*)wob);
    qkv_mfma_k<<<dim3(12, 16), 512, 131072, stream>>>(xb, wqb, cs, qb, kb, vt);
    flash_mfma_k<<<dim3(32, 32), 256, 0, stream>>>(qb, kb, vt, attb);
    proj_mfma_k<<<dim3(8, 32), 256, 0, stream>>>(attb, wob, b_out, out);
}